// Round 1
// baseline (38794.797 us; speedup 1.0000x reference)
//
#include <hip/hip_runtime.h>

// ---------------------------------------------------------------------------
// LSTMDecoder: B=16 S=256 V=32000 H=1024 E=512 DQ=512
// Strategy:
//   - precompute hidden_VQ, hs_proj, loop-invariant gate bases (gbase, h0g)
//   - persistent 255-step kernel (custom grid barrier, 4 syncs/step), fp16
//     MFMA for per-step matmuls, fp32 LSTM state
//   - record [h_t, weighted_t] rows -> ONE big fp16 MFMA GEMM vs pred_W
// ---------------------------------------------------------------------------

typedef _Float16 half8 __attribute__((ext_vector_type(8)));
typedef _Float16 half4 __attribute__((ext_vector_type(4)));
typedef float    f32x4 __attribute__((ext_vector_type(4)));

__device__ __forceinline__ float fast_tanh(float x) {
  x = fminf(fmaxf(x, -15.f), 15.f);
  const float e = __expf(2.f * x);
  return (e - 1.f) * __builtin_amdgcn_rcpf(e + 1.f);
}
__device__ __forceinline__ float fast_sigm(float x) {
  x = fminf(fmaxf(x, -30.f), 30.f);
  return __builtin_amdgcn_rcpf(1.f + __expf(-x));
}

// monotonic-counter grid barrier (bar[0] zeroed by k_init each launch)
__device__ __forceinline__ void grid_sync(unsigned* bar, unsigned target) {
  __syncthreads();
  if (threadIdx.x == 0) {
    __hip_atomic_fetch_add(bar, 1u, __ATOMIC_ACQ_REL, __HIP_MEMORY_SCOPE_AGENT);
    while (__hip_atomic_load(bar, __ATOMIC_ACQUIRE, __HIP_MEMORY_SCOPE_AGENT) < target)
      __builtin_amdgcn_s_sleep(2);
  }
  __syncthreads();
}

// ---- fp32 -> fp16 strided convert: dst[n*Kd+k] = src[n*Ks+off+k] ----------
__global__ __launch_bounds__(256) void k_cvt(_Float16* __restrict__ dst,
                                             const float* __restrict__ src,
                                             int Kd, int Ks, int off, int total4) {
  int i = blockIdx.x * 256 + threadIdx.x;
  if (i >= total4) return;
  int i4 = i << 2;
  int n = i4 / Kd;
  int k = i4 - n * Kd;
  f32x4 s = *(const f32x4*)(src + (size_t)n * Ks + off + k);
  half4 d;
  d[0] = (_Float16)s[0]; d[1] = (_Float16)s[1];
  d[2] = (_Float16)s[2]; d[3] = (_Float16)s[3];
  *(half4*)(dst + (size_t)n * Kd + k) = d;
}

// ---- embedding gather: Ae[(t*16+b)][e] = embed_W[inputs[b,t]][e] ----------
__global__ __launch_bounds__(256) void k_gather(_Float16* __restrict__ Ae,
                                                const float* __restrict__ embedW,
                                                const int* __restrict__ inputs) {
  int i = blockIdx.x * 256 + threadIdx.x;   // over 4096*512/4
  if (i >= 524288) return;
  int i4 = i << 2;
  int r = i4 >> 9;
  int e = i4 & 511;
  int t = r >> 4, b = r & 15;
  half4 d;
  if (t < 255) {
    int tok = inputs[b * 256 + t];
    f32x4 s = *(const f32x4*)(embedW + (size_t)tok * 512 + e);
    d[0] = (_Float16)s[0]; d[1] = (_Float16)s[1];
    d[2] = (_Float16)s[2]; d[3] = (_Float16)s[3];
  } else {
    d[0] = d[1] = d[2] = d[3] = (_Float16)0.f;
  }
  *(half4*)(Ae + (size_t)r * 512 + e) = d;
}

// ---- init: c0/h0 from hidden_VQ[:, -1, :], bsum, Ah tail zero, out[:,0,:]=0,
//      barrier counter = 0 ------------------------------------------------
__global__ __launch_bounds__(256) void k_init(const _Float16* __restrict__ hvq16,
                                              float* cbuf, _Float16* h16, _Float16* h016,
                                              const float* __restrict__ bih,
                                              const float* __restrict__ bhh, float* bsum,
                                              _Float16* Ah, float* out, unsigned* bar) {
  int gi = blockIdx.x * 256 + threadIdx.x;
  if (gi < 16384) {
    int b = gi >> 10, k = gi & 1023;
    float cv = (float)hvq16[(size_t)((b << 8) + 255) * 1024 + k];
    cbuf[gi] = cv;
    float hn = fast_tanh(cv);
    _Float16 hf = (_Float16)hn;
    h16[gi] = hf;
    h016[gi] = hf;
  } else if (gi < 65536) {          // h016 pad rows 16..63 -> 0
    h016[gi] = (_Float16)0.f;
  } else if (gi < 69632) {          // bsum = b_ih + b_hh
    int j = gi - 65536;
    bsum[j] = bih[j] + bhh[j];
  } else if (gi < 102400) {         // Ah rows for t=255 -> 0
    Ah[(size_t)4080 * 2048 + (gi - 69632)] = (_Float16)0.f;
  } else if (gi < 614400) {         // out[:, 0, :] = 0
    int idx = gi - 102400;
    int b = idx / 32000, v = idx - b * 32000;
    out[(size_t)b * 8192000 + v] = 0.f;
  } else if (gi == 614400) {
    bar[0] = 0u;
  }
}

// ---- transpose hidden_VQ16 [16][256][1024] -> hvT16 [16][1024][256] -------
__global__ __launch_bounds__(256) void k_t(const _Float16* __restrict__ in,
                                           _Float16* __restrict__ out) {
  __shared__ _Float16 tile[32][34];
  int b = blockIdx.z, s0 = blockIdx.y << 5, h0 = blockIdx.x << 5;
  int row = threadIdx.x >> 5;     // 0..7
  int col = threadIdx.x & 31;
  #pragma unroll
  for (int rr = 0; rr < 32; rr += 8)
    tile[row + rr][col] = in[(size_t)((b << 8) + s0 + row + rr) * 1024 + h0 + col];
  __syncthreads();
  #pragma unroll
  for (int rr = 0; rr < 32; rr += 8)
    out[(size_t)((b << 10) + h0 + row + rr) * 256 + s0 + col] = tile[col][row + rr];
}

// ---- generic fp16 MFMA GEMM: C[m][n] = sum_k A[m][k]*B[n][k] (+bias[n]) ---
// 64x64 block tile, 4 waves each 16(M)x64(N), 16x16x32 f16 MFMA.
// EPI: 0 = fp16 store, 1 = fp32 store, 2 = scatter to out[b, t+1, :]
template <int EPI, int BIAS>
__global__ __launch_bounds__(256) void k_mfma(const _Float16* __restrict__ A,
                                              const _Float16* __restrict__ Bm,
                                              void* __restrict__ Cout,
                                              const float* __restrict__ bias,
                                              const int N, const int K) {
  __shared__ _Float16 As[64][40];
  __shared__ _Float16 Bs[64][40];
  const int tid  = threadIdx.x;
  const int lane = tid & 63;
  const int wv   = tid >> 6;
  const int quad = lane >> 4;
  const int q8   = quad << 3;
  const int l15  = lane & 15;
  const int m0   = blockIdx.y << 6;
  const int n0   = blockIdx.x << 6;
  const int lr   = tid >> 2;
  const int lc   = (tid & 3) << 3;
  f32x4 acc[4] = {{0.f,0.f,0.f,0.f},{0.f,0.f,0.f,0.f},{0.f,0.f,0.f,0.f},{0.f,0.f,0.f,0.f}};
  for (int kt = 0; kt < K; kt += 32) {
    *(half8*)&As[lr][lc] = *(const half8*)&A[(size_t)(m0 + lr) * K + kt + lc];
    *(half8*)&Bs[lr][lc] = *(const half8*)&Bm[(size_t)(n0 + lr) * K + kt + lc];
    __syncthreads();
    const half8 av = *(const half8*)&As[(wv << 4) + l15][q8];
    #pragma unroll
    for (int nt = 0; nt < 4; ++nt) {
      const half8 bv = *(const half8*)&Bs[(nt << 4) + l15][q8];
      acc[nt] = __builtin_amdgcn_mfma_f32_16x16x32_f16(av, bv, acc[nt], 0, 0, 0);
    }
    __syncthreads();
  }
  #pragma unroll
  for (int nt = 0; nt < 4; ++nt) {
    #pragma unroll
    for (int r = 0; r < 4; ++r) {
      const int row = m0 + (wv << 4) + (quad << 2) + r;
      const int col = n0 + (nt << 4) + l15;
      float v = acc[nt][r];
      if (BIAS) v += bias[col];
      if (EPI == 0) {
        ((_Float16*)Cout)[(size_t)row * N + col] = (_Float16)v;
      } else if (EPI == 1) {
        ((float*)Cout)[(size_t)row * N + col] = v;
      } else {
        const int tt = row >> 4, bb = row & 15;
        if (tt < 255)
          ((float*)Cout)[(size_t)bb * 8192000 + (size_t)(tt + 1) * 32000 + col] = v;
      }
    }
  }
}

// ---- persistent sequential scan (255 steps, 4 grid syncs/step) ------------
// grid MUST be 256 blocks x 256 threads (all co-resident on 256 CUs).
__global__ __launch_bounds__(256) void k_seq(
    const _Float16* __restrict__ hsp16,    // [4096][1024] hs_proj
    const _Float16* __restrict__ hvT16,    // [16][1024][256]
    const _Float16* __restrict__ gbase16,  // [4096][4096]
    const float*    __restrict__ h0g,      // [64][4096] (rows 0..15 used)
    const _Float16* __restrict__ Wh16,     // [1024][1024] attn_W[:, :H]
    const _Float16* __restrict__ Whh16,    // [4096][1024]
    const _Float16* __restrict__ Wihw16,   // [4096][1024] W_ih[:, 512:1536]
    const float*    __restrict__ vvec,     // [1024]
    _Float16* h16, float* cbuf, float* hWh, float* gatesh,
    float* score, _Float16* w16, _Float16* Ah, unsigned* bar) {
  const int tid  = threadIdx.x;
  const int lane = tid & 63;
  const int wv   = tid >> 6;
  const int gw   = (blockIdx.x << 2) | wv;   // global wave 0..1023
  const int quad = lane >> 4;
  const int q8   = quad << 3;
  const int l15  = lane & 15;
  unsigned tgt = 0;
  __shared__ float red[4][4][64][4];

  #pragma unroll 1
  for (int t = 0; t < 255; ++t) {
    // ---- P1: hWh = h @ Wh^T (64 tiles), gatesh = h @ Whh^T (256 tiles) ----
    if (gw < 320) {
      const bool isWh = (gw < 64);
      const int  nt   = isWh ? gw : (gw - 64);
      const int  n0   = nt << 4;
      const _Float16* Bm = isWh ? Wh16 : Whh16;
      const _Float16* ar = h16 + l15 * 1024 + q8;
      const _Float16* br = Bm + (size_t)(n0 + l15) * 1024 + q8;
      f32x4 acc = {0.f, 0.f, 0.f, 0.f};
      for (int kk = 0; kk < 1024; kk += 32)
        acc = __builtin_amdgcn_mfma_f32_16x16x32_f16(
            *(const half8*)(ar + kk), *(const half8*)(br + kk), acc, 0, 0, 0);
      float* Cp = isWh ? hWh : gatesh;
      const int cn = isWh ? 1024 : 4096;
      #pragma unroll
      for (int r = 0; r < 4; ++r)
        Cp[((quad << 2) + r) * cn + n0 + l15] = acc[r];
    }
    tgt += gridDim.x; grid_sync(bar, tgt);

    // ---- P2: score[b,s] = sum_j v[j]*tanh(hWh[b,j] + hs_proj[b,s,j]) ----
    for (int tk = gw; tk < 4096; tk += 1024) {
      const int b = tk >> 8;
      const _Float16* hp = hsp16 + (size_t)tk * 1024;
      const float* hwb = hWh + b * 1024;
      float acc = 0.f;
      #pragma unroll
      for (int g = 0; g < 2; ++g) {
        const int j0 = g * 512 + lane * 8;
        half8 hv = *(const half8*)(hp + j0);
        f32x4 w0 = *(const f32x4*)(hwb + j0);
        f32x4 w1 = *(const f32x4*)(hwb + j0 + 4);
        f32x4 v0 = *(const f32x4*)(vvec + j0);
        f32x4 v1 = *(const f32x4*)(vvec + j0 + 4);
        #pragma unroll
        for (int e = 0; e < 4; ++e) {
          acc += v0[e] * fast_tanh(w0[e] + (float)hv[e]);
          acc += v1[e] * fast_tanh(w1[e] + (float)hv[e + 4]);
        }
      }
      #pragma unroll
      for (int m = 32; m; m >>= 1) acc += __shfl_xor(acc, m, 64);
      if (lane == 0) score[tk] = acc;
    }
    tgt += gridDim.x; grid_sync(bar, tgt);

    // ---- P3: softmax over s + weighted[b,h] = attn . hidden_VQ ----------
    {
      const int t0 = gw << 4;            // 16 (b,h) tasks per wave, same b
      const int b  = t0 >> 10;
      const float* sc = score + (b << 8);
      float s0 = sc[lane], s1 = sc[lane + 64], s2 = sc[lane + 128], s3 = sc[lane + 192];
      float mx = fmaxf(fmaxf(s0, s1), fmaxf(s2, s3));
      #pragma unroll
      for (int m = 32; m; m >>= 1) mx = fmaxf(mx, __shfl_xor(mx, m, 64));
      float e0 = __expf(s0 - mx), e1 = __expf(s1 - mx);
      float e2 = __expf(s2 - mx), e3 = __expf(s3 - mx);
      float z = e0 + e1 + e2 + e3;
      #pragma unroll
      for (int m = 32; m; m >>= 1) z += __shfl_xor(z, m, 64);
      const float inv = __builtin_amdgcn_rcpf(z);
      e0 *= inv; e1 *= inv; e2 *= inv; e3 *= inv;
      const int hbase = t0 & 1023;
      for (int hh = 0; hh < 16; ++hh) {
        const _Float16* pv = hvT16 + (size_t)((b << 10) + hbase + hh) * 256 + lane;
        float a = e0 * (float)pv[0] + e1 * (float)pv[64] +
                  e2 * (float)pv[128] + e3 * (float)pv[192];
        #pragma unroll
        for (int m = 32; m; m >>= 1) a += __shfl_xor(a, m, 64);
        if (lane == 0) {
          const _Float16 af = (_Float16)a;
          w16[(b << 10) + hbase + hh] = af;
          Ah[(size_t)(t * 16 + b) * 2048 + 1024 + hbase + hh] = af;
        }
      }
    }
    tgt += gridDim.x; grid_sync(bar, tgt);

    // ---- P4: gates = gbase + h0g + gatesh + weighted @ Wihw^T; pointwise --
    if (blockIdx.x < 64) {
      const int hj0 = blockIdx.x << 4;
      const int kb  = wv << 8;           // K chunk per wave
      #pragma unroll
      for (int p = 0; p < 4; ++p) {
        const _Float16* ar = w16 + l15 * 1024 + kb + q8;
        const _Float16* br = Wihw16 + (size_t)((p << 10) + hj0 + l15) * 1024 + kb + q8;
        f32x4 acc = {0.f, 0.f, 0.f, 0.f};
        #pragma unroll
        for (int kk = 0; kk < 256; kk += 32)
          acc = __builtin_amdgcn_mfma_f32_16x16x32_f16(
              *(const half8*)(ar + kk), *(const half8*)(br + kk), acc, 0, 0, 0);
        #pragma unroll
        for (int r = 0; r < 4; ++r) red[wv][p][lane][r] = acc[r];
      }
      __syncthreads();
      {
        const int b = tid >> 4, hjl = tid & 15;
        const int ll = ((b >> 2) << 4) + hjl;
        const int rr = b & 3;
        float g4[4];
        #pragma unroll
        for (int p = 0; p < 4; ++p) {
          const int n = (p << 10) + hj0 + hjl;
          g4[p] = red[0][p][ll][rr] + red[1][p][ll][rr] +
                  red[2][p][ll][rr] + red[3][p][ll][rr] +
                  (float)gbase16[(size_t)(t * 16 + b) * 4096 + n] +
                  h0g[b * 4096 + n] + gatesh[b * 4096 + n];
        }
        const float ig = fast_sigm(g4[0]);
        const float fg = fast_sigm(g4[1]);
        const float gg = fast_tanh(g4[2]);
        const float og = fast_sigm(g4[3]);
        const int ci = (b << 10) + hj0 + hjl;
        const float cn2 = fg * cbuf[ci] + ig * gg;
        cbuf[ci] = cn2;
        const float hn = og * fast_tanh(cn2);
        const _Float16 hf = (_Float16)hn;
        h16[ci] = hf;
        Ah[(size_t)(t * 16 + b) * 2048 + hj0 + hjl] = hf;
      }
    }
    tgt += gridDim.x; grid_sync(bar, tgt);
  }
}

// ---------------------------------------------------------------------------
extern "C" void kernel_launch(void* const* d_in, const int* in_sizes, int n_in,
                              void* d_out, int out_size, void* d_ws, size_t ws_size,
                              hipStream_t stream) {
  const int*   inputs  = (const int*)  d_in[0];
  const float* VQembed = (const float*)d_in[1];
  const float* embedW  = (const float*)d_in[2];
  const float* transW  = (const float*)d_in[3];
  const float* attnW   = (const float*)d_in[4];
  const float* attnb   = (const float*)d_in[5];
  const float* vvec    = (const float*)d_in[6];
  const float* Wih     = (const float*)d_in[7];
  const float* Whh     = (const float*)d_in[8];
  const float* bih     = (const float*)d_in[9];
  const float* bhh     = (const float*)d_in[10];
  const float* predW   = (const float*)d_in[11];
  float* out = (float*)d_out;

  char* w = (char*)d_ws;
  size_t off = 0;
  auto take = [&](size_t bytes) -> char* {
    char* p = w + off;
    off = (off + bytes + 255) & ~(size_t)255;
    return p;
  };
  // ~252 MB total workspace
  _Float16* hvq16   = (_Float16*)take(4096ULL * 1024 * 2);   // hidden_VQ fp16
  _Float16* hsp16   = (_Float16*)take(4096ULL * 1024 * 2);   // hs_proj fp16
  _Float16* hvT16   = (_Float16*)take(16ULL * 1024 * 256 * 2);
  _Float16* gbase16 = (_Float16*)take(4096ULL * 4096 * 2);
  float*    h0g     = (float*)   take(64ULL * 4096 * 4);
  _Float16* Ah      = (_Float16*)take(4096ULL * 2048 * 2);   // [h_t, weighted_t]
  _Float16* pw16    = (_Float16*)take(32000ULL * 2048 * 2);
  _Float16* vq16    = (_Float16*)take(4096ULL * 512 * 2);
  _Float16* ae16    = (_Float16*)take(4096ULL * 512 * 2);
  _Float16* tw16    = (_Float16*)take(1024ULL * 512 * 2);
  _Float16* wk16    = (_Float16*)take(1024ULL * 1024 * 2);
  _Float16* wh16    = (_Float16*)take(1024ULL * 1024 * 2);
  _Float16* whh16   = (_Float16*)take(4096ULL * 1024 * 2);
  _Float16* wihe16  = (_Float16*)take(4096ULL * 512 * 2);
  _Float16* wihw16  = (_Float16*)take(4096ULL * 1024 * 2);
  _Float16* wihh016 = (_Float16*)take(4096ULL * 1024 * 2);
  float*    bsum    = (float*)   take(4096ULL * 4);
  float*    cbuf    = (float*)   take(16ULL * 1024 * 4);
  _Float16* h16     = (_Float16*)take(16ULL * 1024 * 2);
  _Float16* h016    = (_Float16*)take(64ULL * 1024 * 2);
  float*    hWh     = (float*)   take(16ULL * 1024 * 4);
  float*    gatesh  = (float*)   take(16ULL * 4096 * 4);
  float*    score   = (float*)   take(4096ULL * 4);
  _Float16* w16     = (_Float16*)take(16ULL * 1024 * 2);
  unsigned* bar     = (unsigned*)take(256);
  (void)ws_size; (void)in_sizes; (void)n_in; (void)out_size;

  auto cvt = [&](_Float16* dst, const float* src, int N, int Kd, int Ks, int o) {
    int total4 = (N * Kd) >> 2;
    k_cvt<<<(total4 + 255) / 256, 256, 0, stream>>>(dst, src, Kd, Ks, o, total4);
  };
  // weight/activation converts (one-time)
  cvt(vq16,    VQembed, 4096,  512,  512,  0);
  cvt(tw16,    transW,  1024,  512,  512,  0);
  cvt(wk16,    attnW,   1024, 1024, 2048, 1024);
  cvt(wh16,    attnW,   1024, 1024, 2048, 0);
  cvt(whh16,   Whh,     4096, 1024, 1024, 0);
  cvt(wihe16,  Wih,     4096,  512, 2560, 0);
  cvt(wihw16,  Wih,     4096, 1024, 2560, 512);
  cvt(wihh016, Wih,     4096, 1024, 2560, 1536);
  cvt(pw16,    predW,  32000, 2048, 2048, 0);
  k_gather<<<2048, 256, 0, stream>>>(ae16, embedW, inputs);

  // hidden_VQ = VQembed @ trans_W^T  (M=4096 N=1024 K=512)
  k_mfma<0, 0><<<dim3(16, 64), 256, 0, stream>>>(vq16, tw16, hvq16, nullptr, 1024, 512);
  // init state (c0/h0 from hidden_VQ[:, -1, :]), biases, zeros, barrier
  k_init<<<2401, 256, 0, stream>>>(hvq16, cbuf, h16, h016, bih, bhh, bsum, Ah, out, bar);
  // transpose for P3 dot layout
  k_t<<<dim3(32, 8, 16), 256, 0, stream>>>(hvq16, hvT16);
  // hs_proj = hidden_VQ @ attn_W[:,H:]^T + attn_b  (M=4096 N=1024 K=1024)
  k_mfma<0, 1><<<dim3(16, 64), 256, 0, stream>>>(hvq16, wk16, hsp16, attnb, 1024, 1024);
  // gbase = we @ W_ih[:, :E]^T  (M=4096 N=4096 K=512)
  k_mfma<0, 0><<<dim3(64, 64), 256, 0, stream>>>(ae16, wihe16, gbase16, nullptr, 4096, 512);
  // h0g = h0 @ W_ih[:, E+H:]^T + (b_ih + b_hh)  (M=64 N=4096 K=1024)
  k_mfma<1, 1><<<dim3(64, 1), 256, 0, stream>>>(h016, wihh016, h0g, bsum, 4096, 1024);

  // sequential 255-step scan
  k_seq<<<256, 256, 0, stream>>>(hsp16, hvT16, gbase16, h0g, wh16, whh16, wihw16,
                                 vvec, h16, cbuf, hWh, gatesh, score, w16, Ah, bar);

  // logits: [h_t, weighted_t] @ pred_W^T -> out[b, t+1, :]  (M=4096 N=32000 K=2048)
  k_mfma<2, 0><<<dim3(500, 64), 256, 0, stream>>>(Ah, pw16, out, nullptr, 32000, 2048);
}